// Round 2
// baseline (128.036 us; speedup 1.0000x reference)
//
#include <hip/hip_runtime.h>

// Problem dims (fixed by the reference)
constexpr int B = 8, T = 64, S = 256, D = 512;

// tanh(x) = (e^{2x}-1)/(e^{2x}+1), e^{2x} = 2^{2x*log2(e)}
__device__ __forceinline__ float fast_tanh(float x) {
    float t = fminf(x * 2.8853900817779268f, 100.0f);  // clamp avoids inf/inf
    float e = __builtin_amdgcn_exp2f(t);               // v_exp_f32
    return (e - 1.0f) * __builtin_amdgcn_rcpf(e + 1.0f);
}

// ---------------- 1) acc = cumsum(source,1)/(1..T) * mask ----------------
__global__ __launch_bounds__(128) void k_acc(const float* __restrict__ src,
                                             const float* __restrict__ mask,
                                             float* __restrict__ acc) {
    int idx = blockIdx.x * 128 + threadIdx.x;  // over B*D
    int b = idx >> 9;          // /D
    int d = idx & (D - 1);
    const float* sp = src + (size_t)b * T * D + d;
    const float* mp = mask + b * T;
    float* ap = acc + (size_t)b * T * D + d;
    float run = 0.f;
    for (int t = 0; t < T; ++t) {
        run += sp[(size_t)t * D];
        ap[(size_t)t * D] = run / (float)(t + 1) * mp[t];
    }
}

// ---------------- 2) wv[d] = sum_j Wv[d][j] ----------------
__global__ __launch_bounds__(64) void k_wv(const float* __restrict__ Wv,
                                           float* __restrict__ wv) {
    int d = blockIdx.x;
    int lane = threadIdx.x;
    const float* row = Wv + (size_t)d * D;
    float s = 0.f;
#pragma unroll
    for (int j = 0; j < D / 64; ++j) s += row[lane + j * 64];
#pragma unroll
    for (int off = 32; off; off >>= 1) s += __shfl_down(s, off);
    if (lane == 0) wv[d] = s;
}

// ---------------- 3) part1 = mem@Wc[:D] + bc ; part2 = mem@Wc[D:] ----------------
__global__ __launch_bounds__(256) void k_part(const float* __restrict__ mem,
                                              const float* __restrict__ Wc,
                                              const float* __restrict__ bc,
                                              float* __restrict__ part1,
                                              float* __restrict__ part2) {
    int row = blockIdx.x * 4 + (threadIdx.x >> 6);  // (b*S+s), one wave per row
    int lane = threadIdx.x & 63;
    const float* mrow = mem + (size_t)row * D;
    float a0 = 0, a1 = 0, a2 = 0, a3 = 0;
    for (int d = lane; d < D; d += 64) {
        float m = mrow[d];
        a0 += m * Wc[d * 2 + 0];
        a1 += m * Wc[d * 2 + 1];
        a2 += m * Wc[(D + d) * 2 + 0];
        a3 += m * Wc[(D + d) * 2 + 1];
    }
#pragma unroll
    for (int off = 32; off; off >>= 1) {
        a0 += __shfl_down(a0, off);
        a1 += __shfl_down(a1, off);
        a2 += __shfl_down(a2, off);
        a3 += __shfl_down(a3, off);
    }
    if (lane == 0) {
        part1[row * 2 + 0] = a0 + bc[0];
        part1[row * 2 + 1] = a1 + bc[1];
        part2[row * 2 + 0] = a2;
        part2[row * 2 + 1] = a3;
    }
}

// ---------------- 4) ht = acc @ Wq + bq  (M=N=K=512 f32 tiled GEMM) ----------------
// 32x32 tile per block, 128 threads, 2 rows x 4 cols per thread.
__global__ __launch_bounds__(128) void k_ht(const float* __restrict__ acc,
                                            const float* __restrict__ Wq,
                                            const float* __restrict__ bq,
                                            float* __restrict__ ht) {
    __shared__ float AL[32][34];  // [dd][row]  (transposed; pad -> 8B align + no conflicts)
    __shared__ float BL[32][36];  // [dd][col]  (pad 36: 144B rows keep 16B alignment)
    const int tid = threadIdx.x;
    const int r0 = blockIdx.x * 32;
    const int c0 = blockIdx.y * 32;
    const int tx = tid & 7;    // col group (4 cols)
    const int ty = tid >> 3;   // row group (2 rows)
    float s00 = 0, s01 = 0, s02 = 0, s03 = 0, s10 = 0, s11 = 0, s12 = 0, s13 = 0;
    for (int d0 = 0; d0 < D; d0 += 32) {
        __syncthreads();
#pragma unroll
        for (int k = 0; k < 2; ++k) {
            int idx = tid + k * 128;
            int row = idx >> 3;
            int c4 = (idx & 7) * 4;
            float4 va = *(const float4*)(acc + (size_t)(r0 + row) * D + d0 + c4);
            AL[c4 + 0][row] = va.x; AL[c4 + 1][row] = va.y;
            AL[c4 + 2][row] = va.z; AL[c4 + 3][row] = va.w;
            float4 vb = *(const float4*)(Wq + (size_t)(d0 + row) * D + c0 + c4);
            *(float4*)&BL[row][c4] = vb;
        }
        __syncthreads();
#pragma unroll
        for (int dd = 0; dd < 32; ++dd) {
            float2 a = *(const float2*)&AL[dd][ty * 2];
            float4 bv = *(const float4*)&BL[dd][tx * 4];
            s00 = fmaf(a.x, bv.x, s00); s01 = fmaf(a.x, bv.y, s01);
            s02 = fmaf(a.x, bv.z, s02); s03 = fmaf(a.x, bv.w, s03);
            s10 = fmaf(a.y, bv.x, s10); s11 = fmaf(a.y, bv.y, s11);
            s12 = fmaf(a.y, bv.z, s12); s13 = fmaf(a.y, bv.w, s13);
        }
    }
    int r = r0 + ty * 2, c = c0 + tx * 4;
    float4 bqv = *(const float4*)(bq + c);
    *(float4*)(ht + (size_t)r * D + c) =
        make_float4(s00 + bqv.x, s01 + bqv.y, s02 + bqv.z, s03 + bqv.w);
    *(float4*)(ht + (size_t)(r + 1) * D + c) =
        make_float4(s10 + bqv.x, s11 + bqv.y, s12 + bqv.z, s13 + bqv.w);
}

// ---------------- 5) sum_gate partials: sgp[dq][b,t,s] ----------------
// Tile 32t x 32s per block, 256 threads each own 2x2, d split 4-way over blocks.
__global__ __launch_bounds__(256) void k_fuse(const float* __restrict__ ht,
                                              const float* __restrict__ mem,
                                              const float* __restrict__ wv,
                                              float* __restrict__ sgp) {
    __shared__ float htT[64][34];   // [dd][t-row] transposed, pad 2 -> even stride, no conflicts
    __shared__ float memT[64][34];  // [dd][s-row]
    __shared__ float wvL[64];
    const int tid = threadIdx.x;
    const int sb = blockIdx.x;            // 0..7
    const int tb = blockIdx.y;            // 0..1
    const int bz = blockIdx.z;            // 0..31
    const int b = bz >> 2, dq = bz & 3;   // batch, d-quarter
    const int st = tid & 15, tt = tid >> 4;
    const float* htBase = ht + ((size_t)b * T + tb * 32) * D;
    const float* memBase = mem + ((size_t)b * S + sb * 32) * D;
    float a00 = 0, a01 = 0, a10 = 0, a11 = 0;
#pragma unroll
    for (int c = 0; c < 2; ++c) {
        const int d0 = dq * 128 + c * 64;
        __syncthreads();
#pragma unroll
        for (int k = 0; k < 2; ++k) {
            int idx = tid + k * 256;       // 0..511
            int row = idx >> 4;            // 0..31
            int c4 = (idx & 15) * 4;       // d offset
            float4 vh = *(const float4*)(htBase + (size_t)row * D + d0 + c4);
            htT[c4 + 0][row] = vh.x; htT[c4 + 1][row] = vh.y;
            htT[c4 + 2][row] = vh.z; htT[c4 + 3][row] = vh.w;
            float4 vm = *(const float4*)(memBase + (size_t)row * D + d0 + c4);
            memT[c4 + 0][row] = vm.x; memT[c4 + 1][row] = vm.y;
            memT[c4 + 2][row] = vm.z; memT[c4 + 3][row] = vm.w;
        }
        if (tid < 16) {
            float4 vw = *(const float4*)(wv + d0 + tid * 4);
            wvL[tid * 4 + 0] = vw.x; wvL[tid * 4 + 1] = vw.y;
            wvL[tid * 4 + 2] = vw.z; wvL[tid * 4 + 3] = vw.w;
        }
        __syncthreads();
#pragma unroll 8
        for (int dd = 0; dd < 64; ++dd) {
            float w = wvL[dd];
            float2 h = *(const float2*)&htT[dd][tt * 2];
            float2 m = *(const float2*)&memT[dd][st * 2];
            a00 = fmaf(fast_tanh(h.x + m.x), w, a00);
            a01 = fmaf(fast_tanh(h.x + m.y), w, a01);
            a10 = fmaf(fast_tanh(h.y + m.x), w, a10);
            a11 = fmaf(fast_tanh(h.y + m.y), w, a11);
        }
    }
    const int t0g = tb * 32 + tt * 2, s0g = sb * 32 + st * 2;
    float* o = sgp + ((size_t)dq * B + b) * T * S;
    *(float2*)(o + (size_t)t0g * S + s0g) = make_float2(a00, a01);
    *(float2*)(o + (size_t)(t0g + 1) * S + s0g) = make_float2(a10, a11);
}

// ---------------- 6) h_fuse = part1 + sg*part2 ----------------
__global__ __launch_bounds__(256) void k_epi(const float* __restrict__ sgp,
                                             const float* __restrict__ part1,
                                             const float* __restrict__ part2,
                                             float* __restrict__ out) {
    int idx = blockIdx.x * 256 + threadIdx.x;  // over B*T*S
    constexpr int BTS = B * T * S;
    float sg = sgp[idx] + sgp[idx + BTS] + sgp[idx + 2 * BTS] + sgp[idx + 3 * BTS];
    int s = idx & (S - 1);
    int b = idx >> 14;  // /(T*S)
    float2 p1 = *(const float2*)(part1 + ((size_t)b * S + s) * 2);
    float2 p2 = *(const float2*)(part2 + ((size_t)b * S + s) * 2);
    *(float2*)(out + (size_t)idx * 2) = make_float2(p1.x + sg * p2.x, p1.y + sg * p2.y);
}

extern "C" void kernel_launch(void* const* d_in, const int* in_sizes, int n_in,
                              void* d_out, int out_size, void* d_ws, size_t ws_size,
                              hipStream_t stream) {
    const float* source = (const float*)d_in[0];
    const float* memory = (const float*)d_in[1];
    const float* masks  = (const float*)d_in[2];
    const float* Wq = (const float*)d_in[3];
    const float* bq = (const float*)d_in[4];
    const float* Wv = (const float*)d_in[5];
    const float* Wc = (const float*)d_in[6];
    const float* bc = (const float*)d_in[7];
    float* out = (float*)d_out;
    float* ws = (float*)d_ws;

    // ws layout (floats). acc overlays the sgp area (acc is dead before sgp is written).
    float* ht    = ws;                       // B*T*D = 262144
    float* accp  = ws + B * T * D;           // 262144 (first half of sgp area)
    float* sgp   = ws + B * T * D;           // 4 * B*T*S = 524288
    float* wv    = sgp + 4 * B * T * S;      // 512
    float* part1 = wv + D;                   // B*S*2 = 4096
    float* part2 = part1 + B * S * 2;        // 4096   (total ~3.2 MB)

    k_acc<<<B * D / 128, 128, 0, stream>>>(source, masks, accp);
    k_wv<<<D, 64, 0, stream>>>(Wv, wv);
    k_part<<<B * S / 4, 256, 0, stream>>>(memory, Wc, bc, part1, part2);
    k_ht<<<dim3(16, 16), 128, 0, stream>>>(accp, Wq, bq, ht);
    k_fuse<<<dim3(8, 2, 32), 256, 0, stream>>>(ht, memory, wv, sgp);
    k_epi<<<B * T * S / 256, 256, 0, stream>>>(sgp, part1, part2, out);
}

// Round 3
// 117.607 us; speedup vs baseline: 1.0887x; 1.0887x over previous
//
#include <hip/hip_runtime.h>

// Problem dims (fixed by the reference)
constexpr int B = 8, T = 64, S = 256, D = 512;
// tanh(x) = 1 - 2/(e^{2x}+1);  e^{2x} = exp2(x * 2*log2(e)).
// SCL is folded into ht (at k_ht store) and mem (at LDS staging).
constexpr float SCL = 2.885390081777927f;  // 2*log2(e)

// ---------------- 1) prep: acc | wv | part1/part2 (block-role split) ----------------
// blocks [0,16):    acc = cumsum(source,1)/(1..T) * mask      (one thread per (b,d))
// blocks [16,144):  wv[d] = sum_j Wv[d][j]                    (one wave per row)
// blocks [144,656): part1 = mem@Wc[:D]+bc ; part2 = mem@Wc[D:] (one wave per (b,s))
__global__ __launch_bounds__(256) void k_prep(const float* __restrict__ src,
                                              const float* __restrict__ mask,
                                              const float* __restrict__ Wv,
                                              const float* __restrict__ Wc,
                                              const float* __restrict__ bc,
                                              const float* __restrict__ mem,
                                              float* __restrict__ acc,
                                              float* __restrict__ wv,
                                              float* __restrict__ part1,
                                              float* __restrict__ part2) {
    const int blk = blockIdx.x;
    const int tid = threadIdx.x;
    if (blk < 16) {
        // ---- acc role: register cumsum, loads fully pipelined ----
        int idx = blk * 256 + tid;          // over B*D = 4096
        int b = idx >> 9, d = idx & (D - 1);
        const float* sp = src + (size_t)b * T * D + d;
        float v[T];
#pragma unroll
        for (int t = 0; t < T; ++t) v[t] = sp[(size_t)t * D];
        const float* mp = mask + b * T;
        float* ap = acc + (size_t)b * T * D + d;
        float run = 0.f;
#pragma unroll
        for (int t = 0; t < T; ++t) {
            run += v[t];
            ap[(size_t)t * D] = run * (1.0f / (float)(t + 1)) * mp[t];
        }
    } else if (blk < 144) {
        // ---- wv role ----
        int row = (blk - 16) * 4 + (tid >> 6);
        int lane = tid & 63;
        const float* r = Wv + (size_t)row * D;
        float s = 0.f;
#pragma unroll
        for (int j = 0; j < D / 64; ++j) s += r[lane + j * 64];
#pragma unroll
        for (int off = 32; off; off >>= 1) s += __shfl_down(s, off);
        if (lane == 0) wv[row] = s;
    } else {
        // ---- part role ----
        int row = (blk - 144) * 4 + (tid >> 6);  // (b*S+s)
        int lane = tid & 63;
        const float* mrow = mem + (size_t)row * D;
        float a0 = 0, a1 = 0, a2 = 0, a3 = 0;
        for (int d = lane; d < D; d += 64) {
            float m = mrow[d];
            float2 w1 = *(const float2*)(Wc + d * 2);
            float2 w2 = *(const float2*)(Wc + (D + d) * 2);
            a0 = fmaf(m, w1.x, a0); a1 = fmaf(m, w1.y, a1);
            a2 = fmaf(m, w2.x, a2); a3 = fmaf(m, w2.y, a3);
        }
#pragma unroll
        for (int off = 32; off; off >>= 1) {
            a0 += __shfl_down(a0, off);
            a1 += __shfl_down(a1, off);
            a2 += __shfl_down(a2, off);
            a3 += __shfl_down(a3, off);
        }
        if (lane == 0) {
            part1[row * 2 + 0] = a0 + bc[0];
            part1[row * 2 + 1] = a1 + bc[1];
            part2[row * 2 + 0] = a2;
            part2[row * 2 + 1] = a3;
        }
    }
}

// ---------------- 2) ht = (acc @ Wq + bq) * SCL  (512x512x512 f32 GEMM) ----------------
__global__ __launch_bounds__(128) void k_ht(const float* __restrict__ acc,
                                            const float* __restrict__ Wq,
                                            const float* __restrict__ bq,
                                            float* __restrict__ ht) {
    __shared__ float AL[32][34];  // [dd][row] transposed
    __shared__ float BL[32][36];  // [dd][col]
    const int tid = threadIdx.x;
    const int r0 = blockIdx.x * 32;
    const int c0 = blockIdx.y * 32;
    const int tx = tid & 7;
    const int ty = tid >> 3;
    float s00 = 0, s01 = 0, s02 = 0, s03 = 0, s10 = 0, s11 = 0, s12 = 0, s13 = 0;
    for (int d0 = 0; d0 < D; d0 += 32) {
        __syncthreads();
#pragma unroll
        for (int k = 0; k < 2; ++k) {
            int idx = tid + k * 128;
            int row = idx >> 3;
            int c4 = (idx & 7) * 4;
            float4 va = *(const float4*)(acc + (size_t)(r0 + row) * D + d0 + c4);
            AL[c4 + 0][row] = va.x; AL[c4 + 1][row] = va.y;
            AL[c4 + 2][row] = va.z; AL[c4 + 3][row] = va.w;
            float4 vb = *(const float4*)(Wq + (size_t)(d0 + row) * D + c0 + c4);
            *(float4*)&BL[row][c4] = vb;
        }
        __syncthreads();
#pragma unroll
        for (int dd = 0; dd < 32; ++dd) {
            float2 a = *(const float2*)&AL[dd][ty * 2];
            float4 bv = *(const float4*)&BL[dd][tx * 4];
            s00 = fmaf(a.x, bv.x, s00); s01 = fmaf(a.x, bv.y, s01);
            s02 = fmaf(a.x, bv.z, s02); s03 = fmaf(a.x, bv.w, s03);
            s10 = fmaf(a.y, bv.x, s10); s11 = fmaf(a.y, bv.y, s11);
            s12 = fmaf(a.y, bv.z, s12); s13 = fmaf(a.y, bv.w, s13);
        }
    }
    int r = r0 + ty * 2, c = c0 + tx * 4;
    float4 bqv = *(const float4*)(bq + c);
    *(float4*)(ht + (size_t)r * D + c) = make_float4(
        (s00 + bqv.x) * SCL, (s01 + bqv.y) * SCL, (s02 + bqv.z) * SCL, (s03 + bqv.w) * SCL);
    *(float4*)(ht + (size_t)(r + 1) * D + c) = make_float4(
        (s10 + bqv.x) * SCL, (s11 + bqv.y) * SCL, (s12 + bqv.z) * SCL, (s13 + bqv.w) * SCL);
}

// ---------------- 3) fused gate + epilogue: out = part1 + sum_gate * part2 ----------------
// Grid (8 sb, 4 tb, 8 b) = 256 blocks x 512 threads. Tile 16t x 32s, 1 elem/thread,
// full D accumulated in-block (no sgp intermediate). ht/mem pre-scaled by SCL so
// tanh = 1 - 2*rcp(exp2(h'+m')+1): 4 VALU + 2 trans per element.
__global__ __launch_bounds__(512) void k_fusepi(const float* __restrict__ ht,
                                                const float* __restrict__ mem,
                                                const float* __restrict__ wv,
                                                const float* __restrict__ part1,
                                                const float* __restrict__ part2,
                                                float* __restrict__ out) {
    __shared__ float htT[64][17];   // [dd][t-row], stride 17: 2-way max on stage, b32 reads
    __shared__ float memT[64][34];  // [dd][s-row], stride 34: conflict-free b32 reads
    __shared__ float wvL[64];
    const int tid = threadIdx.x;
    const int sb = blockIdx.x;   // 0..7  (32 s each)
    const int tb = blockIdx.y;   // 0..3  (16 t each)
    const int b  = blockIdx.z;   // 0..7
    const int st = tid & 31;     // s within tile
    const int tt = tid >> 5;     // t within tile (0..15)
    const float* htBase  = ht  + ((size_t)b * T + tb * 16) * D;
    const float* memBase = mem + ((size_t)b * S + sb * 32) * D;
    float a = 0.f;
#pragma unroll 1
    for (int c = 0; c < 8; ++c) {
        const int d0 = c * 64;
        __syncthreads();
        {   // stage mem tile: 32 rows x 64 d, transposed, pre-scaled
            int row = tid >> 4;            // 0..31
            int c4 = (tid & 15) * 4;
            float4 v = *(const float4*)(memBase + (size_t)row * D + d0 + c4);
            memT[c4 + 0][row] = v.x * SCL; memT[c4 + 1][row] = v.y * SCL;
            memT[c4 + 2][row] = v.z * SCL; memT[c4 + 3][row] = v.w * SCL;
        }
        if (tid < 256) {  // stage ht tile: 16 rows x 64 d (already scaled)
            int row = tid >> 4;            // 0..15
            int c4 = (tid & 15) * 4;
            float4 v = *(const float4*)(htBase + (size_t)row * D + d0 + c4);
            htT[c4 + 0][row] = v.x; htT[c4 + 1][row] = v.y;
            htT[c4 + 2][row] = v.z; htT[c4 + 3][row] = v.w;
        } else if (tid < 272) {
            int j = tid - 256;             // 0..15
            float4 v = *(const float4*)(wv + d0 + j * 4);
            wvL[j * 4 + 0] = v.x; wvL[j * 4 + 1] = v.y;
            wvL[j * 4 + 2] = v.z; wvL[j * 4 + 3] = v.w;
        }
        __syncthreads();
#pragma unroll 8
        for (int dd = 0; dd < 64; ++dd) {
            float x = htT[dd][tt] + memT[dd][st];
            float e = __builtin_amdgcn_exp2f(x);
            float r = __builtin_amdgcn_rcpf(e + 1.0f);
            float th = fmaf(-2.0f, r, 1.0f);   // tanh; -> +/-1 as e -> inf/0, no NaN
            a = fmaf(wvL[dd], th, a);
        }
    }
    const int t = tb * 16 + tt, s = sb * 32 + st;
    float2 p1 = *(const float2*)(part1 + ((size_t)b * S + s) * 2);
    float2 p2 = *(const float2*)(part2 + ((size_t)b * S + s) * 2);
    float* o = out + (((size_t)b * T + t) * S + s) * 2;
    *(float2*)o = make_float2(p1.x + a * p2.x, p1.y + a * p2.y);
}

extern "C" void kernel_launch(void* const* d_in, const int* in_sizes, int n_in,
                              void* d_out, int out_size, void* d_ws, size_t ws_size,
                              hipStream_t stream) {
    const float* source = (const float*)d_in[0];
    const float* memory = (const float*)d_in[1];
    const float* masks  = (const float*)d_in[2];
    const float* Wq = (const float*)d_in[3];
    const float* bq = (const float*)d_in[4];
    const float* Wv = (const float*)d_in[5];
    const float* Wc = (const float*)d_in[6];
    const float* bc = (const float*)d_in[7];
    float* out = (float*)d_out;
    float* ws = (float*)d_ws;

    // ws layout (floats): ~2.2 MB total
    float* ht    = ws;                  // B*T*D = 262144
    float* accp  = ht + B * T * D;      // B*T*D = 262144
    float* wv    = accp + B * T * D;    // 512
    float* part1 = wv + D;              // B*S*2 = 4096
    float* part2 = part1 + B * S * 2;   // B*S*2 = 4096

    k_prep<<<16 + 128 + 512, 256, 0, stream>>>(source, masks, Wv, Wc, bc, memory,
                                               accp, wv, part1, part2);
    k_ht<<<dim3(16, 16), 128, 0, stream>>>(accp, Wq, bq, ht);
    k_fusepi<<<dim3(8, 4, 8), 512, 0, stream>>>(ht, memory, wv, part1, part2, out);
}

// Round 4
// 111.827 us; speedup vs baseline: 1.1449x; 1.0517x over previous
//
#include <hip/hip_runtime.h>

constexpr int B = 8, T = 64, S = 256, D = 512;
// tanh(x) = 1 - 2/(e^{2x}+1), e^{2x} = exp2(SCL*x). SCL folded into ht (k2 store)
// and mem (k3 staging).
constexpr float SCL = 2.885390081777927f;  // 2*log2(e)

// ---------- k1: acc = cumsum(src,1)/(1..T)*mask  (hierarchical-redundant) ----------
// grid 128 = (b 8)x(tc 4)x(dc 4); 128 thr; thread owns (b, d). Each block re-reads
// rows [0, 16*tc+16) (2.5x redundancy) so all 128 blocks are independent.
__global__ __launch_bounds__(128) void k1_acc(const float* __restrict__ src,
                                              const float* __restrict__ mask,
                                              float* __restrict__ acc) {
    int blk = blockIdx.x;
    int b = blk >> 4, tc = (blk >> 2) & 3, dc = blk & 3;
    int d = dc * 128 + threadIdx.x;
    const float* sp = src + ((size_t)b * T) * D + d;
    const float* mp = mask + b * T;
    float* ap = acc + ((size_t)b * T) * D + d;
    float run = 0.f;
    for (int ch = 0; ch <= tc; ++ch) {
        float v[16];
#pragma unroll
        for (int i = 0; i < 16; ++i) v[i] = sp[(size_t)(ch * 16 + i) * D];
        if (ch < tc) {
#pragma unroll
            for (int i = 0; i < 16; ++i) run += v[i];
        } else {
#pragma unroll
            for (int i = 0; i < 16; ++i) {
                run += v[i];
                int t = ch * 16 + i;
                ap[(size_t)t * D] = run * __builtin_amdgcn_rcpf((float)(t + 1)) * mp[t];
            }
        }
    }
}

// ---------- k2: role-split — GEMM ht=(acc@Wq+bq)*SCL | wv row-sums | part1/2 ----------
// blocks [0,256): GEMM 32x32 tiles; [256,288): wv (16 rows each); [288,416): part (16 rows).
__global__ __launch_bounds__(128) void k2_htwp(const float* __restrict__ acc,
                                               const float* __restrict__ Wq,
                                               const float* __restrict__ bq,
                                               const float* __restrict__ Wv,
                                               const float* __restrict__ mem,
                                               const float* __restrict__ Wc,
                                               const float* __restrict__ bc,
                                               float* __restrict__ ht,
                                               float* __restrict__ wv,
                                               float* __restrict__ part1,
                                               float* __restrict__ part2) {
    const int blk = blockIdx.x;
    const int tid = threadIdx.x;
    if (blk < 256) {
        __shared__ float AL[32][34];  // [kk][row] transposed
        __shared__ float BL[32][36];  // [kk][col]
        const int r0 = (blk >> 4) * 32;
        const int c0 = (blk & 15) * 32;
        const int tx = tid & 7, ty = tid >> 3;
        float s00 = 0, s01 = 0, s02 = 0, s03 = 0, s10 = 0, s11 = 0, s12 = 0, s13 = 0;
        for (int d0 = 0; d0 < D; d0 += 32) {
            __syncthreads();
#pragma unroll
            for (int k = 0; k < 2; ++k) {
                int idx = tid + k * 128;
                int row = idx >> 3;
                int c4 = (idx & 7) * 4;
                float4 va = *(const float4*)(acc + (size_t)(r0 + row) * D + d0 + c4);
                AL[c4 + 0][row] = va.x; AL[c4 + 1][row] = va.y;
                AL[c4 + 2][row] = va.z; AL[c4 + 3][row] = va.w;
                float4 vb = *(const float4*)(Wq + (size_t)(d0 + row) * D + c0 + c4);
                *(float4*)&BL[row][c4] = vb;
            }
            __syncthreads();
#pragma unroll
            for (int dd = 0; dd < 32; ++dd) {
                float2 a = *(const float2*)&AL[dd][ty * 2];
                float4 bv = *(const float4*)&BL[dd][tx * 4];
                s00 = fmaf(a.x, bv.x, s00); s01 = fmaf(a.x, bv.y, s01);
                s02 = fmaf(a.x, bv.z, s02); s03 = fmaf(a.x, bv.w, s03);
                s10 = fmaf(a.y, bv.x, s10); s11 = fmaf(a.y, bv.y, s11);
                s12 = fmaf(a.y, bv.z, s12); s13 = fmaf(a.y, bv.w, s13);
            }
        }
        int r = r0 + ty * 2, c = c0 + tx * 4;
        float4 bqv = *(const float4*)(bq + c);
        *(float4*)(ht + (size_t)r * D + c) = make_float4(
            (s00 + bqv.x) * SCL, (s01 + bqv.y) * SCL, (s02 + bqv.z) * SCL, (s03 + bqv.w) * SCL);
        *(float4*)(ht + (size_t)(r + 1) * D + c) = make_float4(
            (s10 + bqv.x) * SCL, (s11 + bqv.y) * SCL, (s12 + bqv.z) * SCL, (s13 + bqv.w) * SCL);
    } else if (blk < 288) {
        // wv role: rows (blk-256)*16 .. +15, one wave per row, 8 rows per wave
        int w = tid >> 6, lane = tid & 63;
        int base = (blk - 256) * 16 + w * 8;
        for (int it = 0; it < 8; ++it) {
            int row = base + it;
            const float* r = Wv + (size_t)row * D;
            float s = 0.f;
#pragma unroll
            for (int j = 0; j < D / 64; ++j) s += r[lane + j * 64];
#pragma unroll
            for (int off = 32; off; off >>= 1) s += __shfl_down(s, off);
            if (lane == 0) wv[row] = s;
        }
    } else {
        // part role: rows (blk-288)*16 .. +15 of (b*S+s); one wave per row
        int w = tid >> 6, lane = tid & 63;
        int base = (blk - 288) * 16 + w * 8;
        for (int it = 0; it < 8; ++it) {
            int row = base + it;
            const float* mrow = mem + (size_t)row * D;
            float a0 = 0, a1 = 0, a2 = 0, a3 = 0;
#pragma unroll
            for (int j = 0; j < D / 64; ++j) {
                int d = lane + j * 64;
                float m = mrow[d];
                float2 w1 = *(const float2*)(Wc + d * 2);
                float2 w2 = *(const float2*)(Wc + (D + d) * 2);
                a0 = fmaf(m, w1.x, a0); a1 = fmaf(m, w1.y, a1);
                a2 = fmaf(m, w2.x, a2); a3 = fmaf(m, w2.y, a3);
            }
#pragma unroll
            for (int off = 32; off; off >>= 1) {
                a0 += __shfl_down(a0, off);
                a1 += __shfl_down(a1, off);
                a2 += __shfl_down(a2, off);
                a3 += __shfl_down(a3, off);
            }
            if (lane == 0) {
                part1[row * 2 + 0] = a0 + bc[0];
                part1[row * 2 + 1] = a1 + bc[1];
                part2[row * 2 + 0] = a2;
                part2[row * 2 + 1] = a3;
            }
        }
    }
}

// ---------- k3: gate + epilogue, wave-uniform dd ----------
// grid (sb 8, tb 4, b 8) = 256 blocks x 256 thr. Tile 16t x 32s, full D.
// Wave w covers dd in [16w,16w+16) of each 64-d chunk; lane: ss=lane&7 (4 s),
// tt=lane>>3 (2 t). Per dd per wave: 1 b64 + 1 b128 + 1 b32 LDS read for 512 elems.
__global__ __launch_bounds__(256) void k3_gate(const float* __restrict__ ht,
                                               const float* __restrict__ mem,
                                               const float* __restrict__ wv,
                                               const float* __restrict__ part1,
                                               const float* __restrict__ part2,
                                               float* __restrict__ out) {
    __shared__ float htT[64][18];   // [dd][t], stride 18: 4-way write, clean b64 read
    __shared__ float memT[64][36];  // [dd][s], stride 36: 8-way write, clean b128 read
    __shared__ float wvL[64];
    __shared__ float pt[4][16][33]; // cross-wave partials
    const int tid = threadIdx.x;
    const int sb = blockIdx.x, tb = blockIdx.y, b = blockIdx.z;
    const int lane = tid & 63, w = tid >> 6;
    const int ss = lane & 7, tt = lane >> 3;
    const float* htBase = ht + ((size_t)b * T + tb * 16) * D;
    const float* memBase = mem + ((size_t)b * S + sb * 32) * D;
    const int hrow = tid >> 4;            // 0..15
    const int c4 = (tid & 15) * 4;        // d-offset within chunk
    const int mrow1 = hrow + 16;
    // prologue: chunk-0 prefetch
    float4 ph = *(const float4*)(htBase + (size_t)hrow * D + c4);
    float4 pm0 = *(const float4*)(memBase + (size_t)hrow * D + c4);
    float4 pm1 = *(const float4*)(memBase + (size_t)mrow1 * D + c4);
    float4 pw;
    if (tid < 16) pw = *(const float4*)(wv + tid * 4);
    float a[2][4];
#pragma unroll
    for (int r = 0; r < 2; ++r)
#pragma unroll
        for (int j = 0; j < 4; ++j) a[r][j] = 0.f;
#pragma unroll 1
    for (int c = 0; c < 8; ++c) {
        __syncthreads();  // LDS free from previous compute
        htT[c4 + 0][hrow] = ph.x; htT[c4 + 1][hrow] = ph.y;
        htT[c4 + 2][hrow] = ph.z; htT[c4 + 3][hrow] = ph.w;
        memT[c4 + 0][hrow] = pm0.x * SCL; memT[c4 + 1][hrow] = pm0.y * SCL;
        memT[c4 + 2][hrow] = pm0.z * SCL; memT[c4 + 3][hrow] = pm0.w * SCL;
        memT[c4 + 0][mrow1] = pm1.x * SCL; memT[c4 + 1][mrow1] = pm1.y * SCL;
        memT[c4 + 2][mrow1] = pm1.z * SCL; memT[c4 + 3][mrow1] = pm1.w * SCL;
        if (tid < 16) {
            wvL[tid * 4 + 0] = pw.x; wvL[tid * 4 + 1] = pw.y;
            wvL[tid * 4 + 2] = pw.z; wvL[tid * 4 + 3] = pw.w;
        }
        __syncthreads();
        if (c < 7) {  // issue next-chunk loads early; latency hides under compute
            int d0 = (c + 1) * 64;
            ph = *(const float4*)(htBase + (size_t)hrow * D + d0 + c4);
            pm0 = *(const float4*)(memBase + (size_t)hrow * D + d0 + c4);
            pm1 = *(const float4*)(memBase + (size_t)mrow1 * D + d0 + c4);
            if (tid < 16) pw = *(const float4*)(wv + d0 + tid * 4);
        }
        const int dbase = w * 16;
#pragma unroll
        for (int i = 0; i < 16; ++i) {
            int dd = dbase + i;
            float2 h2 = *(const float2*)&htT[dd][tt * 2];
            float4 m4 = *(const float4*)&memT[dd][ss * 4];
            float wvv = wvL[dd];
            float hs[2] = {h2.x, h2.y};
            float ms[4] = {m4.x, m4.y, m4.z, m4.w};
#pragma unroll
            for (int r = 0; r < 2; ++r)
#pragma unroll
                for (int j = 0; j < 4; ++j) {
                    float e = __builtin_amdgcn_exp2f(hs[r] + ms[j]);
                    float th = fmaf(-2.0f, __builtin_amdgcn_rcpf(e + 1.0f), 1.0f);
                    a[r][j] = fmaf(wvv, th, a[r][j]);
                }
        }
    }
    // cross-wave d-reduce via LDS partials
    __syncthreads();
#pragma unroll
    for (int r = 0; r < 2; ++r)
#pragma unroll
        for (int j = 0; j < 4; ++j) pt[w][tt * 2 + r][ss * 4 + j] = a[r][j];
    __syncthreads();
    const int t = tid >> 4;             // 0..15
    const int s0 = (tid & 15) * 2;      // 0..30 even
    float sg0 = pt[0][t][s0] + pt[1][t][s0] + pt[2][t][s0] + pt[3][t][s0];
    float sg1 = pt[0][t][s0 + 1] + pt[1][t][s0 + 1] + pt[2][t][s0 + 1] + pt[3][t][s0 + 1];
    const int srow = b * S + sb * 32 + s0;
    float4 p1 = *(const float4*)(part1 + (size_t)srow * 2);  // [s0].xy, [s0+1].zw
    float4 p2 = *(const float4*)(part2 + (size_t)srow * 2);
    float* o = out + (((size_t)b * T + tb * 16 + t) * S + sb * 32 + s0) * 2;
    *(float4*)o = make_float4(p1.x + sg0 * p2.x, p1.y + sg0 * p2.y,
                              p1.z + sg1 * p2.z, p1.w + sg1 * p2.w);
}

extern "C" void kernel_launch(void* const* d_in, const int* in_sizes, int n_in,
                              void* d_out, int out_size, void* d_ws, size_t ws_size,
                              hipStream_t stream) {
    const float* source = (const float*)d_in[0];
    const float* memory = (const float*)d_in[1];
    const float* masks  = (const float*)d_in[2];
    const float* Wq = (const float*)d_in[3];
    const float* bq = (const float*)d_in[4];
    const float* Wv = (const float*)d_in[5];
    const float* Wc = (const float*)d_in[6];
    const float* bc = (const float*)d_in[7];
    float* out = (float*)d_out;
    float* ws = (float*)d_ws;

    float* accp  = ws;                  // B*T*D
    float* ht    = accp + B * T * D;    // B*T*D
    float* wv    = ht + B * T * D;      // 512
    float* part1 = wv + D;              // 2048
    float* part2 = part1 + B * S * 2;   // 2048

    k1_acc<<<128, 128, 0, stream>>>(source, masks, accp);
    k2_htwp<<<416, 128, 0, stream>>>(accp, Wq, bq, Wv, memory, Wc, bc,
                                     ht, wv, part1, part2);
    k3_gate<<<dim3(8, 4, 8), 256, 0, stream>>>(ht, memory, wv, part1, part2, out);
}

// Round 7
// 100.601 us; speedup vs baseline: 1.2727x; 1.1116x over previous
//
#include <hip/hip_runtime.h>
#include <hip/hip_bf16.h>

constexpr int B = 8, T = 64, S = 256, D = 512;
// tanh(x) = 1 - 2/(e^{2x}+1), e^{2x} = exp2(SCL*x). SCL folded into ht (k2 epilogue)
// and mem (k3 staging).
constexpr float SCL = 2.885390081777927f;  // 2*log2(e)

typedef __attribute__((ext_vector_type(8))) short bf16x8;
typedef __attribute__((ext_vector_type(4))) float f32x4;

__device__ __forceinline__ unsigned short f2b(float f) {
    __hip_bfloat16 h = __float2bfloat16(f);
    return __builtin_bit_cast(unsigned short, h);
}

// ---------- k1: 4 roles ----------
// [0,128):   acc = cumsum(src,1)/(1..T)*mask -> bf16   (hierarchical-redundant)
// [128,192): WqT bf16 transpose (64x64 tiles via LDS)
// [192,224): wv[d] = row-sums of Wv (16 rows/block)
// [224,352): part1/part2 (16 rows/block)
__global__ __launch_bounds__(128) void k1_prep(const float* __restrict__ src,
                                               const float* __restrict__ mask,
                                               const float* __restrict__ Wq,
                                               const float* __restrict__ Wv,
                                               const float* __restrict__ mem,
                                               const float* __restrict__ Wc,
                                               const float* __restrict__ bc,
                                               __hip_bfloat16* __restrict__ accB,
                                               __hip_bfloat16* __restrict__ WqTB,
                                               float* __restrict__ wv,
                                               float* __restrict__ part1,
                                               float* __restrict__ part2) {
    __shared__ float TS[64][66];
    const int blk = blockIdx.x;
    const int tid = threadIdx.x;
    if (blk < 128) {
        int b = blk >> 4, tc = (blk >> 2) & 3, dc = blk & 3;
        int d = dc * 128 + tid;
        const float* sp = src + ((size_t)b * T) * D + d;
        const float* mp = mask + b * T;
        __hip_bfloat16* ap = accB + ((size_t)b * T) * D + d;
        float run = 0.f;
        for (int ch = 0; ch <= tc; ++ch) {
            float v[16];
#pragma unroll
            for (int i = 0; i < 16; ++i) v[i] = sp[(size_t)(ch * 16 + i) * D];
            if (ch < tc) {
#pragma unroll
                for (int i = 0; i < 16; ++i) run += v[i];
            } else {
#pragma unroll
                for (int i = 0; i < 16; ++i) {
                    run += v[i];
                    int t = ch * 16 + i;
                    float val = run * __builtin_amdgcn_rcpf((float)(t + 1)) * mp[t];
                    ap[(size_t)t * D] = __float2bfloat16(val);
                }
            }
        }
    } else if (blk < 192) {
        // WqT[n][k] = bf16(Wq[k][n]); 64x64 tile
        int tb = blk - 128;
        int r0 = (tb >> 3) * 64, c0 = (tb & 7) * 64;
        int r = tid >> 1, h = tid & 1;
#pragma unroll
        for (int j = 0; j < 8; ++j) {
            int col = h * 32 + j * 4;
            float4 v = *(const float4*)(Wq + (size_t)(r0 + r) * D + c0 + col);
            *(float4*)&TS[r][col] = v;
        }
        __syncthreads();
        int n = tid >> 1;
#pragma unroll
        for (int j = 0; j < 8; ++j) {
            int kk = h * 32 + j * 4;
            ushort4 u;
            u.x = f2b(TS[kk + 0][n]); u.y = f2b(TS[kk + 1][n]);
            u.z = f2b(TS[kk + 2][n]); u.w = f2b(TS[kk + 3][n]);
            *(ushort4*)((unsigned short*)WqTB + (size_t)(c0 + n) * D + r0 + kk) = u;
        }
    } else if (blk < 224) {
        int w = tid >> 6, lane = tid & 63;
        int base = (blk - 192) * 16 + w * 8;
        for (int it = 0; it < 8; ++it) {
            int row = base + it;
            const float* r = Wv + (size_t)row * D;
            float s = 0.f;
#pragma unroll
            for (int j = 0; j < D / 64; ++j) s += r[lane + j * 64];
#pragma unroll
            for (int off = 32; off; off >>= 1) s += __shfl_down(s, off);
            if (lane == 0) wv[row] = s;
        }
    } else {
        int w = tid >> 6, lane = tid & 63;
        int base = (blk - 224) * 16 + w * 8;
        for (int it = 0; it < 8; ++it) {
            int row = base + it;
            const float* mrow = mem + (size_t)row * D;
            float a0 = 0, a1 = 0, a2 = 0, a3 = 0;
#pragma unroll
            for (int j = 0; j < D / 64; ++j) {
                int d = lane + j * 64;
                float m = mrow[d];
                float2 w1 = *(const float2*)(Wc + d * 2);
                float2 w2 = *(const float2*)(Wc + (D + d) * 2);
                a0 = fmaf(m, w1.x, a0); a1 = fmaf(m, w1.y, a1);
                a2 = fmaf(m, w2.x, a2); a3 = fmaf(m, w2.y, a3);
            }
#pragma unroll
            for (int off = 32; off; off >>= 1) {
                a0 += __shfl_down(a0, off);
                a1 += __shfl_down(a1, off);
                a2 += __shfl_down(a2, off);
                a3 += __shfl_down(a3, off);
            }
            if (lane == 0) {
                part1[row * 2 + 0] = a0 + bc[0];
                part1[row * 2 + 1] = a1 + bc[1];
                part2[row * 2 + 0] = a2;
                part2[row * 2 + 1] = a3;
            }
        }
    }
}

// ---------- k2: ht = (accB @ Wq + bq) * SCL via bf16 MFMA ----------
// 256 blocks x 64 thr (1 wave). 32x32 output tile, full K=512 panel in LDS (64KB).
// Staging: global_load_lds w=16, pre-swizzled source (chunk ^= row&7);
// fragment ds_read_b128 uses the same XOR -> 2-way banks (free).
__global__ __launch_bounds__(64) void k2_gemm(const __hip_bfloat16* __restrict__ accB,
                                              const __hip_bfloat16* __restrict__ WqTB,
                                              const float* __restrict__ bq,
                                              float* __restrict__ ht) {
    __shared__ unsigned short Asw[32 * 512];  // [row r0+j][k], k-chunks XOR-swizzled
    __shared__ unsigned short Bsw[32 * 512];  // [col c0+j][k]
    const int tid = threadIdx.x;                // 0..63
    const int r0 = (blockIdx.x >> 4) * 32;
    const int c0 = (blockIdx.x & 15) * 32;
    const unsigned short* Ag = (const unsigned short*)accB;
    const unsigned short* Bg = (const unsigned short*)WqTB;
#pragma unroll
    for (int j = 0; j < 32; ++j) {
        int chunk = tid ^ (j & 7);  // 16B chunk index 0..63
        __builtin_amdgcn_global_load_lds(
            (const __attribute__((address_space(1))) unsigned int*)(Ag + (size_t)(r0 + j) * D + chunk * 8),
            (__attribute__((address_space(3))) unsigned int*)&Asw[j * 512], 16, 0, 0);
        __builtin_amdgcn_global_load_lds(
            (const __attribute__((address_space(1))) unsigned int*)(Bg + (size_t)(c0 + j) * D + chunk * 8),
            (__attribute__((address_space(3))) unsigned int*)&Bsw[j * 512], 16, 0, 0);
    }
    asm volatile("s_waitcnt vmcnt(0)" ::: "memory");
    const int lr = tid & 15;    // frag row/col within 16
    const int g = tid >> 4;     // k-group 0..3
    f32x4 acc00 = {0,0,0,0}, acc01 = {0,0,0,0}, acc10 = {0,0,0,0}, acc11 = {0,0,0,0};
    const char* Ab = (const char*)Asw;
    const char* Bb = (const char*)Bsw;
#pragma unroll
    for (int ks = 0; ks < 16; ++ks) {
        int kc = ks * 4 + g;
        int ra0 = lr, ra1 = 16 + lr;
        bf16x8 a0 = *(const bf16x8*)(Ab + ra0 * 1024 + ((kc ^ (ra0 & 7)) * 16));
        bf16x8 a1 = *(const bf16x8*)(Ab + ra1 * 1024 + ((kc ^ (ra1 & 7)) * 16));
        bf16x8 b0 = *(const bf16x8*)(Bb + ra0 * 1024 + ((kc ^ (ra0 & 7)) * 16));
        bf16x8 b1 = *(const bf16x8*)(Bb + ra1 * 1024 + ((kc ^ (ra1 & 7)) * 16));
        acc00 = __builtin_amdgcn_mfma_f32_16x16x32_bf16(a0, b0, acc00, 0, 0, 0);
        acc01 = __builtin_amdgcn_mfma_f32_16x16x32_bf16(a0, b1, acc01, 0, 0, 0);
        acc10 = __builtin_amdgcn_mfma_f32_16x16x32_bf16(a1, b0, acc10, 0, 0, 0);
        acc11 = __builtin_amdgcn_mfma_f32_16x16x32_bf16(a1, b1, acc11, 0, 0, 0);
    }
    // C/D layout (m89): col = lane&15, row = (lane>>4)*4 + reg
    const int col0 = c0 + lr, col1 = c0 + 16 + lr;
    const int rb = r0 + g * 4;
    float bq0 = bq[col0], bq1 = bq[col1];
#pragma unroll
    for (int r = 0; r < 4; ++r) {
        ht[(size_t)(rb + r) * D + col0]      = (acc00[r] + bq0) * SCL;
        ht[(size_t)(rb + r) * D + col1]      = (acc01[r] + bq1) * SCL;
        ht[(size_t)(rb + 16 + r) * D + col0] = (acc10[r] + bq0) * SCL;
        ht[(size_t)(rb + 16 + r) * D + col1] = (acc11[r] + bq1) * SCL;
    }
}

// ---------- k3: gate + epilogue, wave-uniform dd ----------
// sum_gate = Wsum - 2 * sum_d wv[d] * rcp(exp2(x)+1);  5 instrs/elem.
__global__ __launch_bounds__(256) void k3_gate(const float* __restrict__ ht,
                                               const float* __restrict__ mem,
                                               const float* __restrict__ wv,
                                               const float* __restrict__ part1,
                                               const float* __restrict__ part2,
                                               float* __restrict__ out) {
    __shared__ float htT[64][18];
    __shared__ float memT[64][36];
    __shared__ float wvL[64];
    __shared__ float pt[4][16][33];
    __shared__ float wsL[4];
    const int tid = threadIdx.x;
    const int sb = blockIdx.x, tb = blockIdx.y, b = blockIdx.z;
    const int lane = tid & 63, w = tid >> 6;
    const int ss = lane & 7, tt = lane >> 3;
    const float* htBase = ht + ((size_t)b * T + tb * 16) * D;
    const float* memBase = mem + ((size_t)b * S + sb * 32) * D;
    const int hrow = tid >> 4;
    const int c4 = (tid & 15) * 4;
    const int mrow1 = hrow + 16;
    float4 ph = *(const float4*)(htBase + (size_t)hrow * D + c4);
    float4 pm0 = *(const float4*)(memBase + (size_t)hrow * D + c4);
    float4 pm1 = *(const float4*)(memBase + (size_t)mrow1 * D + c4);
    float4 pw;
    if (tid < 16) pw = *(const float4*)(wv + tid * 4);
    float a[2][4];
#pragma unroll
    for (int r = 0; r < 2; ++r)
#pragma unroll
        for (int j = 0; j < 4; ++j) a[r][j] = 0.f;
    float wsum = 0.f;
#pragma unroll 1
    for (int c = 0; c < 8; ++c) {
        __syncthreads();
        htT[c4 + 0][hrow] = ph.x; htT[c4 + 1][hrow] = ph.y;
        htT[c4 + 2][hrow] = ph.z; htT[c4 + 3][hrow] = ph.w;
        memT[c4 + 0][hrow] = pm0.x * SCL; memT[c4 + 1][hrow] = pm0.y * SCL;
        memT[c4 + 2][hrow] = pm0.z * SCL; memT[c4 + 3][hrow] = pm0.w * SCL;
        memT[c4 + 0][mrow1] = pm1.x * SCL; memT[c4 + 1][mrow1] = pm1.y * SCL;
        memT[c4 + 2][mrow1] = pm1.z * SCL; memT[c4 + 3][mrow1] = pm1.w * SCL;
        if (tid < 16) {
            wvL[tid * 4 + 0] = pw.x; wvL[tid * 4 + 1] = pw.y;
            wvL[tid * 4 + 2] = pw.z; wvL[tid * 4 + 3] = pw.w;
        }
        __syncthreads();
        if (c < 7) {
            int d0 = (c + 1) * 64;
            ph = *(const float4*)(htBase + (size_t)hrow * D + d0 + c4);
            pm0 = *(const float4*)(memBase + (size_t)hrow * D + d0 + c4);
            pm1 = *(const float4*)(memBase + (size_t)mrow1 * D + d0 + c4);
            if (tid < 16) pw = *(const float4*)(wv + d0 + tid * 4);
        }
        const int dbase = w * 16;
#pragma unroll
        for (int i = 0; i < 16; ++i) {
            int dd = dbase + i;
            float2 h2 = *(const float2*)&htT[dd][tt * 2];
            float4 m4 = *(const float4*)&memT[dd][ss * 4];
            float wvv = wvL[dd];
            wsum += wvv;
            float hs[2] = {h2.x, h2.y};
            float ms[4] = {m4.x, m4.y, m4.z, m4.w};
#pragma unroll
            for (int r = 0; r < 2; ++r)
#pragma unroll
                for (int j = 0; j < 4; ++j) {
                    float e = __builtin_amdgcn_exp2f(hs[r] + ms[j]);
                    a[r][j] = fmaf(wvv, __builtin_amdgcn_rcpf(e + 1.0f), a[r][j]);
                }
        }
    }
    __syncthreads();
#pragma unroll
    for (int r = 0; r < 2; ++r)
#pragma unroll
        for (int j = 0; j < 4; ++j) pt[w][tt * 2 + r][ss * 4 + j] = a[r][j];
    if (lane == 0) wsL[w] = wsum;
    __syncthreads();
    const int t = tid >> 4;
    const int s0 = (tid & 15) * 2;
    float Wsum = wsL[0] + wsL[1] + wsL[2] + wsL[3];
    float q0 = pt[0][t][s0] + pt[1][t][s0] + pt[2][t][s0] + pt[3][t][s0];
    float q1 = pt[0][t][s0 + 1] + pt[1][t][s0 + 1] + pt[2][t][s0 + 1] + pt[3][t][s0 + 1];
    float sg0 = fmaf(-2.0f, q0, Wsum);
    float sg1 = fmaf(-2.0f, q1, Wsum);
    const int srow = b * S + sb * 32 + s0;
    float4 p1 = *(const float4*)(part1 + (size_t)srow * 2);
    float4 p2 = *(const float4*)(part2 + (size_t)srow * 2);
    float* o = out + (((size_t)b * T + tb * 16 + t) * S + sb * 32 + s0) * 2;
    *(float4*)o = make_float4(p1.x + sg0 * p2.x, p1.y + sg0 * p2.y,
                              p1.z + sg1 * p2.z, p1.w + sg1 * p2.w);
}

extern "C" void kernel_launch(void* const* d_in, const int* in_sizes, int n_in,
                              void* d_out, int out_size, void* d_ws, size_t ws_size,
                              hipStream_t stream) {
    const float* source = (const float*)d_in[0];
    const float* memory = (const float*)d_in[1];
    const float* masks  = (const float*)d_in[2];
    const float* Wq = (const float*)d_in[3];
    const float* bq = (const float*)d_in[4];
    const float* Wv = (const float*)d_in[5];
    const float* Wc = (const float*)d_in[6];
    const float* bc = (const float*)d_in[7];
    float* out = (float*)d_out;
    char* w = (char*)d_ws;

    __hip_bfloat16* accB = (__hip_bfloat16*)w;                    // 512 KB
    __hip_bfloat16* WqTB = (__hip_bfloat16*)(w + (512 << 10));    // 512 KB
    float* ht    = (float*)(w + (1024 << 10));                    // 1 MB
    float* wv    = (float*)(w + (2048 << 10));                    // 2 KB
    float* part1 = wv + D;                                        // 16 KB
    float* part2 = part1 + B * S * 2;

    k1_prep<<<352, 128, 0, stream>>>(source, masks, Wq, Wv, memory, Wc, bc,
                                     accB, WqTB, wv, part1, part2);
    k2_gemm<<<256, 64, 0, stream>>>(accB, WqTB, bq, ht);
    k3_gate<<<dim3(8, 4, 8), 256, 0, stream>>>(ht, memory, wv, part1, part2, out);
}

// Round 8
// 99.982 us; speedup vs baseline: 1.2806x; 1.0062x over previous
//
#include <hip/hip_runtime.h>
#include <hip/hip_bf16.h>

constexpr int B = 8, T = 64, S = 256, D = 512;
// tanh(x) = 1 - 2/(e^{2x}+1), e^{2x} = exp2(SCL*x). SCL folded into ht (k2 epilogue)
// and mem (k3 staging).
constexpr float SCL = 2.885390081777927f;  // 2*log2(e)

typedef __attribute__((ext_vector_type(8))) short bf16x8;
typedef __attribute__((ext_vector_type(4))) float f32x4;

__device__ __forceinline__ unsigned short f2b(float f) {
    __hip_bfloat16 h = __float2bfloat16(f);
    return __builtin_bit_cast(unsigned short, h);
}

// ---------- k1: 4 roles ----------
// [0,128):   acc = cumsum(src,1)/(1..T)*mask -> bf16   (hierarchical-redundant)
// [128,192): WqT bf16 transpose (64x64 tiles via LDS)
// [192,224): wv[d] = row-sums of Wv (16 rows/block)
// [224,352): part1/part2 (16 rows/block)
__global__ __launch_bounds__(128) void k1_prep(const float* __restrict__ src,
                                               const float* __restrict__ mask,
                                               const float* __restrict__ Wq,
                                               const float* __restrict__ Wv,
                                               const float* __restrict__ mem,
                                               const float* __restrict__ Wc,
                                               const float* __restrict__ bc,
                                               __hip_bfloat16* __restrict__ accB,
                                               __hip_bfloat16* __restrict__ WqTB,
                                               float* __restrict__ wv,
                                               float* __restrict__ part1,
                                               float* __restrict__ part2) {
    __shared__ float TS[64][66];
    const int blk = blockIdx.x;
    const int tid = threadIdx.x;
    if (blk < 128) {
        int b = blk >> 4, tc = (blk >> 2) & 3, dc = blk & 3;
        int d = dc * 128 + tid;
        const float* sp = src + ((size_t)b * T) * D + d;
        const float* mp = mask + b * T;
        __hip_bfloat16* ap = accB + ((size_t)b * T) * D + d;
        float run = 0.f;
        for (int ch = 0; ch <= tc; ++ch) {
            float v[16];
#pragma unroll
            for (int i = 0; i < 16; ++i) v[i] = sp[(size_t)(ch * 16 + i) * D];
            if (ch < tc) {
#pragma unroll
                for (int i = 0; i < 16; ++i) run += v[i];
            } else {
#pragma unroll
                for (int i = 0; i < 16; ++i) {
                    run += v[i];
                    int t = ch * 16 + i;
                    float val = run * __builtin_amdgcn_rcpf((float)(t + 1)) * mp[t];
                    ap[(size_t)t * D] = __float2bfloat16(val);
                }
            }
        }
    } else if (blk < 192) {
        // WqT[n][k] = bf16(Wq[k][n]); 64x64 tile
        int tb = blk - 128;
        int r0 = (tb >> 3) * 64, c0 = (tb & 7) * 64;
        int r = tid >> 1, h = tid & 1;
#pragma unroll
        for (int j = 0; j < 8; ++j) {
            int col = h * 32 + j * 4;
            float4 v = *(const float4*)(Wq + (size_t)(r0 + r) * D + c0 + col);
            *(float4*)&TS[r][col] = v;
        }
        __syncthreads();
        int n = tid >> 1;
#pragma unroll
        for (int j = 0; j < 8; ++j) {
            int kk = h * 32 + j * 4;
            ushort4 u;
            u.x = f2b(TS[kk + 0][n]); u.y = f2b(TS[kk + 1][n]);
            u.z = f2b(TS[kk + 2][n]); u.w = f2b(TS[kk + 3][n]);
            *(ushort4*)((unsigned short*)WqTB + (size_t)(c0 + n) * D + r0 + kk) = u;
        }
    } else if (blk < 224) {
        int w = tid >> 6, lane = tid & 63;
        int base = (blk - 192) * 16 + w * 8;
        for (int it = 0; it < 8; ++it) {
            int row = base + it;
            const float* r = Wv + (size_t)row * D;
            float s = 0.f;
#pragma unroll
            for (int j = 0; j < D / 64; ++j) s += r[lane + j * 64];
#pragma unroll
            for (int off = 32; off; off >>= 1) s += __shfl_down(s, off);
            if (lane == 0) wv[row] = s;
        }
    } else {
        int w = tid >> 6, lane = tid & 63;
        int base = (blk - 224) * 16 + w * 8;
        for (int it = 0; it < 8; ++it) {
            int row = base + it;
            const float* mrow = mem + (size_t)row * D;
            float a0 = 0, a1 = 0, a2 = 0, a3 = 0;
#pragma unroll
            for (int j = 0; j < D / 64; ++j) {
                int d = lane + j * 64;
                float m = mrow[d];
                float2 w1 = *(const float2*)(Wc + d * 2);
                float2 w2 = *(const float2*)(Wc + (D + d) * 2);
                a0 = fmaf(m, w1.x, a0); a1 = fmaf(m, w1.y, a1);
                a2 = fmaf(m, w2.x, a2); a3 = fmaf(m, w2.y, a3);
            }
#pragma unroll
            for (int off = 32; off; off >>= 1) {
                a0 += __shfl_down(a0, off);
                a1 += __shfl_down(a1, off);
                a2 += __shfl_down(a2, off);
                a3 += __shfl_down(a3, off);
            }
            if (lane == 0) {
                part1[row * 2 + 0] = a0 + bc[0];
                part1[row * 2 + 1] = a1 + bc[1];
                part2[row * 2 + 0] = a2;
                part2[row * 2 + 1] = a3;
            }
        }
    }
}

// ---------- k2: ht = (accB @ Wq + bq) * SCL via bf16 MFMA ----------
// 256 blocks x 64 thr (1 wave). 32x32 output tile, full K=512 panel in LDS (64KB).
__global__ __launch_bounds__(64) void k2_gemm(const __hip_bfloat16* __restrict__ accB,
                                              const __hip_bfloat16* __restrict__ WqTB,
                                              const float* __restrict__ bq,
                                              float* __restrict__ ht) {
    __shared__ unsigned short Asw[32 * 512];  // [row r0+j][k], k-chunks XOR-swizzled
    __shared__ unsigned short Bsw[32 * 512];  // [col c0+j][k]
    const int tid = threadIdx.x;                // 0..63
    const int r0 = (blockIdx.x >> 4) * 32;
    const int c0 = (blockIdx.x & 15) * 32;
    const unsigned short* Ag = (const unsigned short*)accB;
    const unsigned short* Bg = (const unsigned short*)WqTB;
#pragma unroll
    for (int j = 0; j < 32; ++j) {
        int chunk = tid ^ (j & 7);  // 16B chunk index 0..63
        __builtin_amdgcn_global_load_lds(
            (const __attribute__((address_space(1))) unsigned int*)(Ag + (size_t)(r0 + j) * D + chunk * 8),
            (__attribute__((address_space(3))) unsigned int*)&Asw[j * 512], 16, 0, 0);
        __builtin_amdgcn_global_load_lds(
            (const __attribute__((address_space(1))) unsigned int*)(Bg + (size_t)(c0 + j) * D + chunk * 8),
            (__attribute__((address_space(3))) unsigned int*)&Bsw[j * 512], 16, 0, 0);
    }
    asm volatile("s_waitcnt vmcnt(0)" ::: "memory");
    const int lr = tid & 15;    // frag row/col within 16
    const int g = tid >> 4;     // k-group 0..3
    f32x4 acc00 = {0,0,0,0}, acc01 = {0,0,0,0}, acc10 = {0,0,0,0}, acc11 = {0,0,0,0};
    const char* Ab = (const char*)Asw;
    const char* Bb = (const char*)Bsw;
#pragma unroll
    for (int ks = 0; ks < 16; ++ks) {
        int kc = ks * 4 + g;
        int ra0 = lr, ra1 = 16 + lr;
        bf16x8 a0 = *(const bf16x8*)(Ab + ra0 * 1024 + ((kc ^ (ra0 & 7)) * 16));
        bf16x8 a1 = *(const bf16x8*)(Ab + ra1 * 1024 + ((kc ^ (ra1 & 7)) * 16));
        bf16x8 b0 = *(const bf16x8*)(Bb + ra0 * 1024 + ((kc ^ (ra0 & 7)) * 16));
        bf16x8 b1 = *(const bf16x8*)(Bb + ra1 * 1024 + ((kc ^ (ra1 & 7)) * 16));
        acc00 = __builtin_amdgcn_mfma_f32_16x16x32_bf16(a0, b0, acc00, 0, 0, 0);
        acc01 = __builtin_amdgcn_mfma_f32_16x16x32_bf16(a0, b1, acc01, 0, 0, 0);
        acc10 = __builtin_amdgcn_mfma_f32_16x16x32_bf16(a1, b0, acc10, 0, 0, 0);
        acc11 = __builtin_amdgcn_mfma_f32_16x16x32_bf16(a1, b1, acc11, 0, 0, 0);
    }
    // C/D layout (m89): col = lane&15, row = (lane>>4)*4 + reg
    const int col0 = c0 + lr, col1 = c0 + 16 + lr;
    const int rb = r0 + g * 4;
    float bq0 = bq[col0], bq1 = bq[col1];
#pragma unroll
    for (int r = 0; r < 4; ++r) {
        ht[(size_t)(rb + r) * D + col0]      = (acc00[r] + bq0) * SCL;
        ht[(size_t)(rb + r) * D + col1]      = (acc01[r] + bq1) * SCL;
        ht[(size_t)(rb + 16 + r) * D + col0] = (acc10[r] + bq0) * SCL;
        ht[(size_t)(rb + 16 + r) * D + col1] = (acc11[r] + bq1) * SCL;
    }
}

// ---------- k3: gate + epilogue, 8 waves (2 waves/SIMD) ----------
// grid (sb 8, tb 4, b 8) = 256 blocks x 512 thr. Tile 16t x 32s, d split 8-way
// across waves (wave w owns dd in [8w, 8w+8) of each 64-chunk). Lane: 2t x 4s.
// sum_gate = Wsum - 2 * sum_d wv[d] * rcp(exp2(x)+1)
__global__ __launch_bounds__(512) void k3_gate(const float* __restrict__ ht,
                                               const float* __restrict__ mem,
                                               const float* __restrict__ wv,
                                               const float* __restrict__ part1,
                                               const float* __restrict__ part2,
                                               float* __restrict__ out) {
    __shared__ float htT[64][18];   // [dd][t], b64-aligned reads
    __shared__ float memT[64][36];  // [dd][s], b128-aligned reads
    __shared__ float wvL[64];
    __shared__ float pt[8][16][33]; // cross-wave partials
    __shared__ float wsL[8];
    const int tid = threadIdx.x;
    const int sb = blockIdx.x, tb = blockIdx.y, b = blockIdx.z;
    const int lane = tid & 63, w = tid >> 6;
    const int ss = lane & 7, tt = lane >> 3;
    const float* htBase = ht + ((size_t)b * T + tb * 16) * D;
    const float* memBase = mem + ((size_t)b * S + sb * 32) * D;
    const int srow = tid >> 4;            // staging row 0..31
    const int c4 = (tid & 15) * 4;        // staging d-offset
    // prologue: chunk-0 prefetch
    float4 ph, pw;
    if (tid < 256) ph = *(const float4*)(htBase + (size_t)srow * D + c4);
    float4 pm = *(const float4*)(memBase + (size_t)srow * D + c4);
    if (tid < 16) pw = *(const float4*)(wv + tid * 4);
    float a[2][4];
#pragma unroll
    for (int r = 0; r < 2; ++r)
#pragma unroll
        for (int j = 0; j < 4; ++j) a[r][j] = 0.f;
    float wsum = 0.f;
#pragma unroll 1
    for (int c = 0; c < 8; ++c) {
        __syncthreads();  // LDS free from previous compute
        if (tid < 256) {
            htT[c4 + 0][srow] = ph.x; htT[c4 + 1][srow] = ph.y;
            htT[c4 + 2][srow] = ph.z; htT[c4 + 3][srow] = ph.w;
        }
        memT[c4 + 0][srow] = pm.x * SCL; memT[c4 + 1][srow] = pm.y * SCL;
        memT[c4 + 2][srow] = pm.z * SCL; memT[c4 + 3][srow] = pm.w * SCL;
        if (tid < 16) {
            wvL[tid * 4 + 0] = pw.x; wvL[tid * 4 + 1] = pw.y;
            wvL[tid * 4 + 2] = pw.z; wvL[tid * 4 + 3] = pw.w;
        }
        __syncthreads();
        if (c < 7) {  // issue next-chunk loads early; latency hides under compute
            int d0 = (c + 1) * 64;
            if (tid < 256) ph = *(const float4*)(htBase + (size_t)srow * D + d0 + c4);
            pm = *(const float4*)(memBase + (size_t)srow * D + d0 + c4);
            if (tid < 16) pw = *(const float4*)(wv + d0 + tid * 4);
        }
        const int dbase = w * 8;
#pragma unroll
        for (int i = 0; i < 8; ++i) {
            int dd = dbase + i;
            float2 h2 = *(const float2*)&htT[dd][tt * 2];
            float4 m4 = *(const float4*)&memT[dd][ss * 4];
            float wvv = wvL[dd];
            wsum += wvv;
            float hs[2] = {h2.x, h2.y};
            float ms[4] = {m4.x, m4.y, m4.z, m4.w};
#pragma unroll
            for (int r = 0; r < 2; ++r)
#pragma unroll
                for (int j = 0; j < 4; ++j) {
                    float e = __builtin_amdgcn_exp2f(hs[r] + ms[j]);
                    a[r][j] = fmaf(wvv, __builtin_amdgcn_rcpf(e + 1.0f), a[r][j]);
                }
        }
    }
    __syncthreads();
#pragma unroll
    for (int r = 0; r < 2; ++r)
#pragma unroll
        for (int j = 0; j < 4; ++j) pt[w][tt * 2 + r][ss * 4 + j] = a[r][j];
    if (lane == 0) wsL[w] = wsum;
    __syncthreads();
    const int t = tid >> 5;             // 0..15
    const int s = tid & 31;             // 0..31
    float Wsum = 0.f;
#pragma unroll
    for (int k = 0; k < 8; ++k) Wsum += wsL[k];
    float q = 0.f;
#pragma unroll
    for (int k = 0; k < 8; ++k) q += pt[k][t][s];
    float sg = fmaf(-2.0f, q, Wsum);
    const int sg_row = b * S + sb * 32 + s;
    float2 p1 = *(const float2*)(part1 + (size_t)sg_row * 2);
    float2 p2 = *(const float2*)(part2 + (size_t)sg_row * 2);
    float* o = out + (((size_t)b * T + tb * 16 + t) * S + sb * 32 + s) * 2;
    *(float2*)o = make_float2(p1.x + sg * p2.x, p1.y + sg * p2.y);
}

extern "C" void kernel_launch(void* const* d_in, const int* in_sizes, int n_in,
                              void* d_out, int out_size, void* d_ws, size_t ws_size,
                              hipStream_t stream) {
    const float* source = (const float*)d_in[0];
    const float* memory = (const float*)d_in[1];
    const float* masks  = (const float*)d_in[2];
    const float* Wq = (const float*)d_in[3];
    const float* bq = (const float*)d_in[4];
    const float* Wv = (const float*)d_in[5];
    const float* Wc = (const float*)d_in[6];
    const float* bc = (const float*)d_in[7];
    float* out = (float*)d_out;
    char* w = (char*)d_ws;

    __hip_bfloat16* accB = (__hip_bfloat16*)w;                    // 512 KB
    __hip_bfloat16* WqTB = (__hip_bfloat16*)(w + (512 << 10));    // 512 KB
    float* ht    = (float*)(w + (1024 << 10));                    // 1 MB
    float* wv    = (float*)(w + (2048 << 10));                    // 2 KB
    float* part1 = wv + D;                                        // 16 KB
    float* part2 = part1 + B * S * 2;

    k1_prep<<<352, 128, 0, stream>>>(source, masks, Wq, Wv, memory, Wc, bc,
                                     accB, WqTB, wv, part1, part2);
    k2_gemm<<<256, 64, 0, stream>>>(accB, WqTB, bq, ht);
    k3_gate<<<dim3(8, 4, 8), 512, 0, stream>>>(ht, memory, wv, part1, part2, out);
}